// Round 14
// baseline (328.845 us; speedup 1.0000x reference)
//
#include <hip/hip_runtime.h>

#define CH 128
#define DS 24
#define HW (DS*DS)      // 576
#define VS (DS*DS*DS)   // 13824

typedef _Float16 f16x8 __attribute__((ext_vector_type(8)));
typedef _Float16 half2v __attribute__((ext_vector_type(2)));
typedef __attribute__((ext_vector_type(4))) float f32x4;
typedef _Float16 h4 __attribute__((ext_vector_type(4)));

__device__ __forceinline__ half2v u2h(unsigned u) {
  union { unsigned u; half2v h; } v; v.u = u; return v.h;
}
__device__ __forceinline__ unsigned h2u(half2v h) {
  union { unsigned u; half2v h; } v; v.h = h; return v.u;
}

// ---------------------------------------------------------------------------
// K0: weight prep, coalesced via LDS transpose.
// ---------------------------------------------------------------------------
__global__ __launch_bounds__(256) void prep_weights(
    const float* __restrict__ w_off, const float* __restrict__ w_def,
    const float* __restrict__ w1,
    _Float16* __restrict__ WTh, _Float16* __restrict__ WDh,
    _Float16* __restrict__ W1h) {
  __shared__ float sbuf[3456];
  const int b = blockIdx.x, t = threadIdx.x;
  if (b < 96) {
    const int o = b;
    if (o < 81) {
      for (int s = t; s < 3456; s += 256) sbuf[s] = w_off[o*3456 + s];
      __syncthreads();
      for (int s = t; s < 3456; s += 256) {
        int k = s >> 7, c = s & 127;
        WTh[(k*96 + o)*128 + c] = (_Float16)sbuf[c*27 + k];
      }
    } else {
      for (int s = t; s < 3456; s += 256) {
        int k = s >> 7, c = s & 127;
        WTh[(k*96 + o)*128 + c] = (_Float16)0.f;
      }
    }
  } else if (b < 224) {
    const int o = b - 96;
    for (int s = t; s < 3456; s += 256) sbuf[s] = w_def[o*3456 + s];
    __syncthreads();
    for (int s = t; s < 3456; s += 256) {
      int k = s >> 7, c = s & 127;
      WDh[(k*128 + o)*128 + c] = (_Float16)sbuf[c*27 + k];
    }
  } else {
    for (int s = t; s < 16384; s += 256) W1h[s] = (_Float16)w1[s];
  }
}

// ---------------------------------------------------------------------------
// K1: depthwise 5x5x5, pad=2 — LDS-free row-register version.
// ---------------------------------------------------------------------------
__global__ __launch_bounds__(192) void dw5_kernel(
    const float* __restrict__ x, const float* __restrict__ w0,
    const float* __restrict__ b0, float* __restrict__ A1) {
  const int c  = blockIdx.x / 3;
  const int zb = (blockIdx.x % 3) * 8;
  __shared__ float sw[125];
  const int t = threadIdx.x;
  if (t < 125) sw[t] = w0[c*125 + t];
  __syncthreads();
  const int z = zb + t / 24, y = t % 24;
  const float* xc = x + c*VS;
  float acc[24];
  #pragma unroll
  for (int o = 0; o < 24; ++o) acc[o] = 0.f;
  #pragma unroll
  for (int kz = 0; kz < 5; ++kz) {
    int zz = z + kz - 2;
    if ((unsigned)zz >= 24u) continue;
    #pragma unroll
    for (int ky = 0; ky < 5; ++ky) {
      int yy = y + ky - 2;
      if ((unsigned)yy >= 24u) continue;
      const float* row = &xc[(zz*DS + yy)*DS];
      float f[24];
      #pragma unroll
      for (int q = 0; q < 6; ++q) {
        float4 r = *(const float4*)(row + 4*q);
        f[4*q] = r.x; f[4*q+1] = r.y; f[4*q+2] = r.z; f[4*q+3] = r.w;
      }
      const float* wr = &sw[(kz*5 + ky)*5];
      #pragma unroll
      for (int kx = 0; kx < 5; ++kx) {
        float w = wr[kx];
        #pragma unroll
        for (int o = 0; o < 24; ++o) {
          int xi = o + kx - 2;
          if (xi >= 0 && xi < 24) acc[o] = fmaf(w, f[xi], acc[o]);
        }
      }
    }
  }
  const float bias = b0[c];
  float* orow = &A1[c*VS + (z*DS + y)*DS];
  #pragma unroll
  for (int q = 0; q < 6; ++q)
    *(float4*)(orow + 4*q) = make_float4(acc[4*q]+bias, acc[4*q+1]+bias,
                                         acc[4*q+2]+bias, acc[4*q+3]+bias);
}

// ---------------------------------------------------------------------------
// K2: depthwise 5x5x5 dil=3 pad=6 — LDS-free + fused fp16 transpose store.
// ---------------------------------------------------------------------------
__global__ __launch_bounds__(192) void dwdil_kernel(
    const float* __restrict__ A1, const float* __restrict__ wgt,
    const float* __restrict__ bs, _Float16* __restrict__ A2th) {
  const int c  = blockIdx.x / 3;
  const int zb = (blockIdx.x % 3) * 8;
  __shared__ float sw[125];
  const int t = threadIdx.x;
  if (t < 125) sw[t] = wgt[c*125 + t];
  __syncthreads();
  const int z = zb + t / 24, y = t % 24;
  const float* xc = A1 + c*VS;
  float acc[24];
  #pragma unroll
  for (int o = 0; o < 24; ++o) acc[o] = 0.f;
  #pragma unroll
  for (int kz = 0; kz < 5; ++kz) {
    int zz = z + 3*kz - 6;
    if ((unsigned)zz >= 24u) continue;
    #pragma unroll
    for (int ky = 0; ky < 5; ++ky) {
      int yy = y + 3*ky - 6;
      if ((unsigned)yy >= 24u) continue;
      const float* row = &xc[(zz*DS + yy)*DS];
      float f[24];
      #pragma unroll
      for (int q = 0; q < 6; ++q) {
        float4 r = *(const float4*)(row + 4*q);
        f[4*q] = r.x; f[4*q+1] = r.y; f[4*q+2] = r.z; f[4*q+3] = r.w;
      }
      const float* wr = &sw[(kz*5 + ky)*5];
      #pragma unroll
      for (int kx = 0; kx < 5; ++kx) {
        float w = wr[kx];
        #pragma unroll
        for (int o = 0; o < 24; ++o) {
          int xi = o + 3*kx - 6;
          if (xi >= 0 && xi < 24) acc[o] = fmaf(w, f[xi], acc[o]);
        }
      }
    }
  }
  const float bias = bs[c];
  _Float16* dst = &A2th[(z*DS + y)*DS*CH + c];
  #pragma unroll
  for (int o = 0; o < 24; ++o)
    dst[o*CH] = (_Float16)(acc[o] + bias);
}

// ---------------------------------------------------------------------------
// K4: offset conv, f16 MFMA, 64-v tiles, 384 thr / 6 waves (wave = m-tile,
// A-frags direct from global).  Double-buffered Bl, single barrier per tap.
// Per-thread chunk coords HOISTED (r12 recomputed v/576 etc. per tap).
// ---------------------------------------------------------------------------
__global__ __launch_bounds__(384, 5) void offconv_kernel(
    const _Float16* __restrict__ A2th, const _Float16* __restrict__ WTh,
    _Float16* __restrict__ OFFp) {
  const int vb = (blockIdx.x % 216) * 64;
  const int kg = blockIdx.x / 216;          // 0..2
  __shared__ __align__(16) _Float16 Bl[2][64*128];  // 32 KB
  const int t    = threadIdx.x;
  const int lane = t & 63, w = t >> 6;      // w 0..5 = m-tile
  const int l16  = lane & 15, quad = lane >> 4;
  const int cq   = t & 15;                  // 384 % 16 == 0 -> same all slots
  const bool has3 = (t < 256);
  int pvv[3], pvl[3], pz[3], py[3], px[3];
  #pragma unroll
  for (int j = 0; j < 3; ++j) {
    int s  = t + 384*j;
    int vl = (s >> 4) & 63;
    int v  = vb + vl;
    pvl[j] = vl; pvv[j] = v;
    pz[j] = v / HW; py[j] = (v / DS) % DS; px[j] = v % DS;
  }
  f32x4 acc[4];
  #pragma unroll
  for (int n = 0; n < 4; ++n) acc[n] = (f32x4){0.f,0.f,0.f,0.f};

  const int k0 = kg*9;
  {  // prologue: stage B(k0) -> Bl[0]
    const int dz = k0/9 - 1, dy = (k0/3)%3 - 1, dx = k0%3 - 1;
    const int doff = (dz*DS + dy)*DS + dx;
    #pragma unroll
    for (int j = 0; j < 3; ++j) {
      uint4 pk = {0u,0u,0u,0u};
      int zz = pz[j]+dz, yy = py[j]+dy, xq = px[j]+dx;
      if ((j < 2 || has3) && (unsigned)zz < 24u && (unsigned)yy < 24u &&
          (unsigned)xq < 24u)
        pk = *(const uint4*)&A2th[(pvv[j] + doff)*CH + (cq << 3)];
      if (j < 2 || has3)
        *(uint4*)&Bl[0][pvl[j]*128 + ((cq ^ (pvl[j] & 15)) << 3)] = pk;
    }
  }
  __syncthreads();

  for (int i = 0; i < 9; ++i) {
    const int k = k0 + i, bi = i & 1;
    f16x8 af[4];
    #pragma unroll
    for (int ks = 0; ks < 4; ++ks)
      af[ks] = *(const f16x8*)&WTh[(k*96 + (w << 4) + l16)*128 + (ks << 5) + (quad << 3)];
    uint4 cc[3];
    if (i < 8) {
      const int kn = k + 1;
      const int dz = kn/9 - 1, dy = (kn/3)%3 - 1, dx = kn%3 - 1;
      const int doff = (dz*DS + dy)*DS + dx;
      #pragma unroll
      for (int j = 0; j < 3; ++j) {
        uint4 pk = {0u,0u,0u,0u};
        int zz = pz[j]+dz, yy = py[j]+dy, xq = px[j]+dx;
        if ((j < 2 || has3) && (unsigned)zz < 24u && (unsigned)yy < 24u &&
            (unsigned)xq < 24u)
          pk = *(const uint4*)&A2th[(pvv[j] + doff)*CH + (cq << 3)];
        cc[j] = pk;
      }
    }
    #pragma unroll
    for (int ks = 0; ks < 4; ++ks) {
      int gx = (((ks << 2) + quad) ^ l16) << 3;
      #pragma unroll
      for (int n = 0; n < 4; ++n) {
        f16x8 bf = *(const f16x8*)&Bl[bi][((n << 4) + l16)*128 + gx];
        acc[n] = __builtin_amdgcn_mfma_f32_16x16x32_f16(af[ks], bf, acc[n], 0, 0, 0);
      }
    }
    if (i < 8) {
      #pragma unroll
      for (int j = 0; j < 3; ++j)
        if (j < 2 || has3)
          *(uint4*)&Bl[bi ^ 1][pvl[j]*128 + ((cq ^ (pvl[j] & 15)) << 3)] = cc[j];
      __syncthreads();
    }
  }
  #pragma unroll
  for (int n = 0; n < 4; ++n)
    #pragma unroll
    for (int r = 0; r < 4; ++r) {
      int o = (w << 4) + (quad << 2) + r;
      if (o < 81)
        OFFp[(kg*81 + o)*VS + vb + (n << 4) + l16] = (_Float16)acc[n][r];
    }
}

// ---------------------------------------------------------------------------
// K5: deformable conv — BARRIER-FREE / LDS-FREE.  1-wave (64-thr) blocks:
// grid = 216 vt x 4 n-tiles x 5 kg = 4320 free-running waves (~17/CU).
// Each lane (quad,l16) gathers its OWN MFMA B-fragment into registers
// (voxel 16nb+l16, channels 32ks+8quad — exact Bl-swizzle semantics),
// meta computed in-register (quad-redundant), A-frags from global per
// (m,ks).  Zero LDS, zero __syncthreads -> waves at random phases so
// VALU/L1/MFMA pipes can finally overlap across waves.
// ---------------------------------------------------------------------------
__global__ __launch_bounds__(64) void deform_kernel(
    const _Float16* __restrict__ A2th, const _Float16* __restrict__ OFFp,
    const float* __restrict__ b_off, const _Float16* __restrict__ WDh,
    _Float16* __restrict__ D0, _Float16* __restrict__ D1,
    _Float16* __restrict__ D2, _Float16* __restrict__ D3,
    _Float16* __restrict__ D4) {
  const int bid = blockIdx.x;
  const int vt  = bid % 216;
  const int nb  = (bid / 216) & 3;
  const int kg  = bid / 864;                 // 0..4
  _Float16* DP = (kg == 0) ? D0 : (kg == 1) ? D1 : (kg == 2) ? D2
               : (kg == 3) ? D3 : D4;
  const int nt = (kg < 2) ? 6 : 5;                    // sizes 6,6,5,5,5
  const int k0 = (kg < 2) ? kg*6 : 12 + (kg - 2)*5;   // 0,6,12,17,22
  const int lane = threadIdx.x;
  const int l16  = lane & 15, quad = lane >> 4;
  const int v = vt*64 + nb*16 + l16;         // this lane's voxel (B n-index)
  const int z = v / HW, y = (v / DS) % DS, x = v % DS;

  f32x4 acc[8];
  #pragma unroll
  for (int m = 0; m < 8; ++m) acc[m] = (f32x4){0.f,0.f,0.f,0.f};

  for (int i = 0; i < nt; ++i) {
    const int k = k0 + i;
    // offsets: 3 partials + bias per axis
    const int r0 = 3*k;
    float po0 = b_off[r0]   + (float)OFFp[(r0    )*VS + v]
              + (float)OFFp[(81 + r0)*VS + v] + (float)OFFp[(162 + r0)*VS + v];
    float po1 = b_off[r0+1] + (float)OFFp[(r0 + 1)*VS + v]
              + (float)OFFp[(82 + r0)*VS + v] + (float)OFFp[(163 + r0)*VS + v];
    float po2 = b_off[r0+2] + (float)OFFp[(r0 + 2)*VS + v]
              + (float)OFFp[(83 + r0)*VS + v] + (float)OFFp[(164 + r0)*VS + v];
    // trilinear meta, all 8 corners in-register
    float cz = (float)(z + k/9     - 1) + po0;
    float cy = (float)(y + (k/3)%3 - 1) + po1;
    float cx = (float)(x + k%3     - 1) + po2;
    float fz = floorf(cz), fy = floorf(cy), fx = floorf(cx);
    int iz = (int)fz, iy = (int)fy, ix = (int)fx;
    float rz = cz - fz, ry = cy - fy, rx = cx - fx;
    half2v wp8[8]; int id8[8];
    #pragma unroll
    for (int c8 = 0; c8 < 8; ++c8) {
      int ca = c8 >> 2, cb = (c8 >> 1) & 1, cc2 = c8 & 1;
      int zi = iz + ca, yi = iy + cb, xi = ix + cc2;
      float ww = (ca ? rz : 1.f-rz) * (cb ? ry : 1.f-ry) * (cc2 ? rx : 1.f-rx);
      bool valid = ((unsigned)zi < 24u) && ((unsigned)yi < 24u) && ((unsigned)xi < 24u);
      float wv = valid ? ww : 0.f;
      wp8[c8] = (half2v){(_Float16)wv, (_Float16)wv};
      id8[c8] = valid ? ((zi*DS + yi)*DS + xi) * 128 : 0;
    }
    // gather this lane's B-fragments for 4 k-steps
    f16x8 bf[4];
    #pragma unroll
    for (int ks = 0; ks < 4; ++ks) {
      const int cofs = (ks << 5) + (quad << 3);
      half2v b0 = {(_Float16)0.f, (_Float16)0.f};
      half2v b1 = b0, b2 = b0, b3 = b0;
      #pragma unroll
      for (int c8 = 0; c8 < 8; ++c8) {
        uint4 g = *(const uint4*)&A2th[id8[c8] + cofs];
        half2v wp = wp8[c8];
        b0 += u2h(g.x) * wp;
        b1 += u2h(g.y) * wp;
        b2 += u2h(g.z) * wp;
        b3 += u2h(g.w) * wp;
      }
      union { uint4 u; f16x8 h; } pk;
      pk.u = make_uint4(h2u(b0), h2u(b1), h2u(b2), h2u(b3));
      bf[ks] = pk.h;
    }
    // MFMA: A-frags streamed from global (L2-resident W)
    #pragma unroll
    for (int ks = 0; ks < 4; ++ks) {
      const _Float16* wbase = &WDh[k*CH*CH + (ks << 5) + (quad << 3)];
      #pragma unroll
      for (int m = 0; m < 8; ++m) {
        f16x8 af = *(const f16x8*)&wbase[((m << 4) + l16)*CH];
        acc[m] = __builtin_amdgcn_mfma_f32_16x16x32_f16(af, bf[ks], acc[m], 0, 0, 0);
      }
    }
  }
  #pragma unroll
  for (int m = 0; m < 8; ++m)
    #pragma unroll
    for (int r = 0; r < 4; ++r) {
      int o = (m << 4) + (quad << 2) + r;
      DP[o*VS + v] = (_Float16)acc[m][r];
    }
}

// ---------------------------------------------------------------------------
// K6: f16 MFMA 1x1x1 conv + x-multiply, 32-v tiles -> grid 432.
// Bl = D0+..+D4+b_def (fp16 partial sum).
// ---------------------------------------------------------------------------
__global__ __launch_bounds__(256) void pw_mul_kernel(
    const _Float16* __restrict__ D0, const _Float16* __restrict__ D1,
    const _Float16* __restrict__ D2, const _Float16* __restrict__ D3,
    const _Float16* __restrict__ D4, const float* __restrict__ b_def,
    const _Float16* __restrict__ W1h, const float* __restrict__ b1,
    const float* __restrict__ x, float* __restrict__ out) {
  const int vb = blockIdx.x * 32;
  __shared__ __align__(16) _Float16 Wl[128*128]; // 32 KB
  __shared__ __align__(16) _Float16 Bl[32*128];  // 8 KB
  const int t    = threadIdx.x;
  const int lane = t & 63, w = t >> 6;
  const int l16  = lane & 15, quad = lane >> 4;
  const int wo = t >> 4, wcg = t & 15;
  #pragma unroll
  for (int i = 0; i < 8; ++i) {
    int o = wo + 16*i;
    *(uint4*)&Wl[o*128 + ((wcg ^ (o & 15)) << 3)] =
        *(const uint4*)&W1h[o*128 + (wcg << 3)];
  }
  {
    const int vsq = t & 7;     // v = 4*vsq..4*vsq+3
    const int c0  = t >> 3;    // c = c0 + 32*i
    #pragma unroll
    for (int i = 0; i < 4; ++i) {
      int c = c0 + (i << 5);
      float bd = b_def[c];
      int base = c*VS + vb + (vsq << 2);
      h4 a0 = *(const h4*)&D0[base];
      h4 a1 = *(const h4*)&D1[base];
      h4 a2 = *(const h4*)&D2[base];
      h4 a3 = *(const h4*)&D3[base];
      h4 a4 = *(const h4*)&D4[base];
      #pragma unroll
      for (int j = 0; j < 4; ++j) {
        float sum = (float)a0[j] + (float)a1[j] + (float)a2[j]
                  + (float)a3[j] + (float)a4[j] + bd;
        int row = (vsq << 2) + j;
        Bl[row*128 + (((c >> 3) ^ (row & 15)) << 3) + (c & 7)] = (_Float16)sum;
      }
    }
  }
  __syncthreads();
  f32x4 acc[2][2];
  #pragma unroll
  for (int i = 0; i < 2; ++i)
    #pragma unroll
    for (int n = 0; n < 2; ++n) acc[i][n] = (f32x4){0.f,0.f,0.f,0.f};
  #pragma unroll
  for (int ks = 0; ks < 4; ++ks) {
    int gx = (((ks << 2) + quad) ^ l16) << 3;
    f16x8 a0 = *(const f16x8*)&Wl[((w << 5) + l16)*128 + gx];
    f16x8 a1 = *(const f16x8*)&Wl[((w << 5) + 16 + l16)*128 + gx];
    #pragma unroll
    for (int n = 0; n < 2; ++n) {
      f16x8 bf = *(const f16x8*)&Bl[((n << 4) + l16)*128 + gx];
      acc[0][n] = __builtin_amdgcn_mfma_f32_16x16x32_f16(a0, bf, acc[0][n], 0, 0, 0);
      acc[1][n] = __builtin_amdgcn_mfma_f32_16x16x32_f16(a1, bf, acc[1][n], 0, 0, 0);
    }
  }
  #pragma unroll
  for (int i = 0; i < 2; ++i)
    #pragma unroll
    for (int n = 0; n < 2; ++n)
      #pragma unroll
      for (int r = 0; r < 4; ++r) {
        int o = (w << 5) + (i << 4) + (quad << 2) + r;
        int vv = vb + (n << 4) + l16;
        out[o*VS + vv] = x[o*VS + vv] * (acc[i][n][r] + b1[o]);
      }
}

// ---------------------------------------------------------------------------
// Workspace (floats, total 7,383,296 f = 29.5 MB):
//   [0        , 1769472)  A1 fp32 (dw5 out) -> later D0,D1 fp16
//   [1769472  , 2654208)  A2th [V][128] fp16
//   [2654208  , 4333824)  OFFp [3][81][V] fp16
//   [4333824  , 5218560)  D2 fp16
//   [5218560  , 6103296)  D3 fp16
//   [6103296  , 6988032)  D4 fp16
//   [6988032  , 7383296)  WTh fp16 | WDh fp16 | W1h fp16
// ---------------------------------------------------------------------------
extern "C" void kernel_launch(void* const* d_in, const int* in_sizes, int n_in,
                              void* d_out, int out_size, void* d_ws, size_t ws_size,
                              hipStream_t stream) {
  (void)in_sizes; (void)n_in; (void)out_size; (void)ws_size;
  const float* x     = (const float*)d_in[0];
  const float* w0    = (const float*)d_in[1];
  const float* b0    = (const float*)d_in[2];
  const float* wsw   = (const float*)d_in[3];
  const float* bs    = (const float*)d_in[4];
  const float* w_off = (const float*)d_in[5];
  const float* b_off = (const float*)d_in[6];
  const float* w_def = (const float*)d_in[7];
  const float* b_def = (const float*)d_in[8];
  const float* w1    = (const float*)d_in[9];
  const float* b1    = (const float*)d_in[10];
  float* out = (float*)d_out;

  float* wsf = (float*)d_ws;
  float*     A1   = wsf;
  _Float16*  A2th = (_Float16*)(wsf + 1769472);
  _Float16*  OFFp = (_Float16*)(wsf + 2654208);
  _Float16*  D2   = (_Float16*)(wsf + 4333824);
  _Float16*  D3   = (_Float16*)(wsf + 5218560);
  _Float16*  D4   = (_Float16*)(wsf + 6103296);
  _Float16*  WTh  = (_Float16*)(wsf + 6988032);
  _Float16*  WDh  = WTh + 331776;
  _Float16*  W1h  = WDh + 442368;
  _Float16*  D0   = (_Float16*)A1;          // A1 dead after dwdil
  _Float16*  D1   = D0 + 128*VS;

  prep_weights  <<<225,  256, 0, stream>>>(w_off, w_def, w1, WTh, WDh, W1h);
  dw5_kernel    <<<384,  192, 0, stream>>>(x, w0, b0, A1);
  dwdil_kernel  <<<384,  192, 0, stream>>>(A1, wsw, bs, A2th);
  offconv_kernel<<<648,  384, 0, stream>>>(A2th, WTh, OFFp);
  deform_kernel <<<4320, 64,  0, stream>>>(A2th, OFFp, b_off, WDh,
                                           D0, D1, D2, D3, D4);
  pw_mul_kernel <<<432,  256, 0, stream>>>(D0, D1, D2, D3, D4, b_def,
                                           W1h, b1, x, out);
}